// Round 2
// baseline (463.586 us; speedup 1.0000x reference)
//
#include <hip/hip_runtime.h>

typedef __attribute__((ext_vector_type(8))) short short8;
typedef __attribute__((ext_vector_type(4))) float f32x4;

constexpr int Bb = 256, Ss = 512, Kk = 32, Ff = 64, H1 = 512, H2 = 256;
constexpr int Mtot = Bb * Ss;   // 131072
constexpr int KD1 = Kk * Ff;    // 2048

#define DEVI static __device__ __forceinline__

DEVI unsigned short f2b(float f) {
  unsigned u = __float_as_uint(f);
  return (unsigned short)((u + 0x7FFFu + ((u >> 16) & 1u)) >> 16);
}

DEVI void stage16(const void* g, void* l) {
  __builtin_amdgcn_global_load_lds((const __attribute__((address_space(1))) void*)g,
                                   (__attribute__((address_space(3))) void*)l, 16, 0, 0);
}

// ---------- precompute kernels ----------
__global__ void k_cvt_x(const float* __restrict__ x, unsigned short* __restrict__ xbf) {
  int i = blockIdx.x * 256 + threadIdx.x;  // over 2097152 float4 groups
  float4 v = ((const float4*)x)[i];
  ushort4 o;
  o.x = f2b(v.x); o.y = f2b(v.y); o.z = f2b(v.z); o.w = f2b(v.w);
  ((ushort4*)xbf)[i] = o;
}

// w1t[h][k*64+f] = W1[k*65+f][h]  (strip distance rows, transpose, bf16)
__global__ void k_w1t(const float* __restrict__ W1, unsigned short* __restrict__ w1t) {
  int idx = blockIdx.x * 256 + threadIdx.x;  // 512*2048
  int h = idx >> 11, i = idx & 2047;
  int k = i >> 6, f = i & 63;
  w1t[idx] = f2b(W1[(k * 65 + f) * 512 + h]);
}

// w2t[n][k] = W2[k][n]
__global__ void k_w2t(const float* __restrict__ W2, unsigned short* __restrict__ w2t) {
  int idx = blockIdx.x * 256 + threadIdx.x;  // 256*512
  int n = idx >> 9, k = idx & 511;
  w2t[idx] = f2b(W2[k * 256 + n]);
}

// dbias[s][h] = b1[h] + sum_k dist[s][k] * W1[k*65+64][h]   (fp32)
__global__ void k_dbias(const float* __restrict__ W1, const float* __restrict__ b1,
                        const float* __restrict__ dist, float* __restrict__ dbias) {
  int idx = blockIdx.x * 256 + threadIdx.x;  // 512*512
  int s = idx >> 9, h = idx & 511;
  float a = b1[h];
  #pragma unroll
  for (int k = 0; k < 32; ++k)
    a += dist[s * 32 + k] * W1[(k * 65 + 64) * 512 + h];
  dbias[idx] = a;
}

// ---------- GEMM1: h1 = relu(gather(xbf) @ w1t^T + dbias), M=131072 N=512 K=2048 ----------
__global__ __launch_bounds__(256, 2) void k_gemm1(
    const unsigned short* __restrict__ xbf, const unsigned short* __restrict__ w1t,
    const int* __restrict__ nb, const float* __restrict__ dbias,
    unsigned short* __restrict__ h1) {
  __shared__ __align__(16) unsigned short As[128 * 64];
  __shared__ __align__(16) unsigned short Bs[128 * 64];
  const int tid = threadIdx.x;
  const int lane = tid & 63;
  const int w = tid >> 6;
  const int wm = w >> 1, wn = w & 1;
  const int mblk = blockIdx.x >> 2;
  const int nblk = blockIdx.x & 3;
  const int r0 = mblk << 7;        // base bs row; single batch b per tile (128 | 512)
  const int b = r0 >> 9;
  const int s0 = r0 & 511;
  const int ncol0 = nblk << 7;
  const int arow = lane >> 3;          // row within 8-row staging group
  const int acol = (lane & 7) << 3;    // bf16 element offset (16B chunks)

  f32x4 acc[4][4];
  #pragma unroll
  for (int m = 0; m < 4; ++m)
    #pragma unroll
    for (int n = 0; n < 4; ++n) acc[m][n] = (f32x4){0.f, 0.f, 0.f, 0.f};

  for (int t = 0; t < 32; ++t) {       // K-step = one neighbor's 64 features
    #pragma unroll
    for (int i = 0; i < 4; ++i) {      // A: gather rows xbf[b, nb[s,t], :]
      int rr = (w << 5) + (i << 3);
      int row = rr + arow;
      int j = nb[((s0 + row) << 5) + t];
      stage16(xbf + (((size_t)((b << 9) + j)) << 6) + acol, As + rr * 64);
    }
    #pragma unroll
    for (int i = 0; i < 4; ++i) {      // B^T tile: w1t rows ncol0..+127, k-cols t*64..+63
      int rr = (w << 5) + (i << 3);
      int row = rr + arow;
      stage16(w1t + (((size_t)(ncol0 + row)) << 11) + (t << 6) + acol, Bs + rr * 64);
    }
    __syncthreads();
    #pragma unroll
    for (int ks = 0; ks < 2; ++ks) {
      short8 af[4], bfr[4];
      #pragma unroll
      for (int m = 0; m < 4; ++m)
        af[m] = *(const short8*)(As + ((wm << 6) + (m << 4) + (lane & 15)) * 64 + (ks << 5) + ((lane >> 4) << 3));
      #pragma unroll
      for (int n = 0; n < 4; ++n)
        bfr[n] = *(const short8*)(Bs + ((wn << 6) + (n << 4) + (lane & 15)) * 64 + (ks << 5) + ((lane >> 4) << 3));
      #pragma unroll
      for (int m = 0; m < 4; ++m)
        #pragma unroll
        for (int n = 0; n < 4; ++n)
          acc[m][n] = __builtin_amdgcn_mfma_f32_16x16x32_bf16(af[m], bfr[n], acc[m][n], 0, 0, 0);
    }
    __syncthreads();
  }

  #pragma unroll
  for (int m = 0; m < 4; ++m) {
    int rowl = (wm << 6) + (m << 4) + ((lane >> 4) << 2);
    #pragma unroll
    for (int n = 0; n < 4; ++n) {
      int col = ncol0 + (wn << 6) + (n << 4) + (lane & 15);
      #pragma unroll
      for (int r = 0; r < 4; ++r) {
        int row = r0 + rowl + r;
        float v = acc[m][n][r] + dbias[((row & 511) << 9) + col];
        v = v > 0.f ? v : 0.f;
        h1[((size_t)row << 9) + col] = f2b(v);
      }
    }
  }
}

// ---------- GEMM2 + fused max-over-S: M=131072 N=256 K=512 ----------
__global__ __launch_bounds__(256, 2) void k_gemm2(
    const unsigned short* __restrict__ h1, const unsigned short* __restrict__ w2t,
    const float* __restrict__ b2, unsigned* __restrict__ mrelu) {
  __shared__ __align__(16) unsigned short As[128 * 64];
  __shared__ __align__(16) unsigned short Bs[128 * 64];
  const int tid = threadIdx.x;
  const int lane = tid & 63;
  const int w = tid >> 6;
  const int wm = w >> 1, wn = w & 1;
  const int mblk = blockIdx.x >> 1;
  const int nblk = blockIdx.x & 1;
  const int r0 = mblk << 7;
  const int b = r0 >> 9;
  const int ncol0 = nblk << 7;
  const int arow = lane >> 3;
  const int acol = (lane & 7) << 3;

  f32x4 acc[4][4];
  #pragma unroll
  for (int m = 0; m < 4; ++m)
    #pragma unroll
    for (int n = 0; n < 4; ++n) acc[m][n] = (f32x4){0.f, 0.f, 0.f, 0.f};

  for (int t = 0; t < 8; ++t) {
    #pragma unroll
    for (int i = 0; i < 4; ++i) {
      int rr = (w << 5) + (i << 3);
      int row = rr + arow;
      stage16(h1 + (((size_t)(r0 + row)) << 9) + (t << 6) + acol, As + rr * 64);
      stage16(w2t + (((size_t)(ncol0 + row)) << 9) + (t << 6) + acol, Bs + rr * 64);
    }
    __syncthreads();
    #pragma unroll
    for (int ks = 0; ks < 2; ++ks) {
      short8 af[4], bfr[4];
      #pragma unroll
      for (int m = 0; m < 4; ++m)
        af[m] = *(const short8*)(As + ((wm << 6) + (m << 4) + (lane & 15)) * 64 + (ks << 5) + ((lane >> 4) << 3));
      #pragma unroll
      for (int n = 0; n < 4; ++n)
        bfr[n] = *(const short8*)(Bs + ((wn << 6) + (n << 4) + (lane & 15)) * 64 + (ks << 5) + ((lane >> 4) << 3));
      #pragma unroll
      for (int m = 0; m < 4; ++m)
        #pragma unroll
        for (int n = 0; n < 4; ++n)
          acc[m][n] = __builtin_amdgcn_mfma_f32_16x16x32_bf16(af[m], bfr[n], acc[m][n], 0, 0, 0);
    }
    __syncthreads();
  }

  // column max over this wave's 64 rows, then atomicMax into per-batch table
  #pragma unroll
  for (int n = 0; n < 4; ++n) {
    int col = ncol0 + (wn << 6) + (n << 4) + (lane & 15);
    float cm = -1e30f;
    #pragma unroll
    for (int m = 0; m < 4; ++m)
      #pragma unroll
      for (int r = 0; r < 4; ++r) cm = fmaxf(cm, acc[m][n][r]);
    cm = fmaxf(cm, __shfl_xor(cm, 16));
    cm = fmaxf(cm, __shfl_xor(cm, 32));
    if ((lane >> 4) == 0) {
      float v = fmaxf(cm + b2[col], 0.f);   // relu folded: table init 0, bits monotone for >=0
      atomicMax(mrelu + ((b << 8) + col), __float_as_uint(v));
    }
  }
}

// ---------- final: out[b] = relu(m[b,:]) . Wd + bd  (fp32) ----------
__global__ void k_final(const unsigned* __restrict__ mrelu, const float* __restrict__ wd,
                        const float* __restrict__ bd, float* __restrict__ out) {
  int b = blockIdx.x, t = threadIdx.x;
  float v = __uint_as_float(mrelu[(b << 8) + t]) * wd[t];
  #pragma unroll
  for (int o = 32; o > 0; o >>= 1) v += __shfl_down(v, o);
  __shared__ float p[4];
  if ((t & 63) == 0) p[t >> 6] = v;
  __syncthreads();
  if (t == 0) out[b] = p[0] + p[1] + p[2] + p[3] + bd[0];
}

extern "C" void kernel_launch(void* const* d_in, const int* in_sizes, int n_in,
                              void* d_out, int out_size, void* d_ws, size_t ws_size,
                              hipStream_t stream) {
  (void)in_sizes; (void)n_in; (void)out_size; (void)ws_size;
  const float* x    = (const float*)d_in[0];
  const int*   nb   = (const int*)d_in[1];
  const float* dist = (const float*)d_in[2];
  const float* W1   = (const float*)d_in[3];
  const float* b1   = (const float*)d_in[4];
  const float* W2   = (const float*)d_in[5];
  const float* b2   = (const float*)d_in[6];
  const float* Wd   = (const float*)d_in[7];
  const float* bd   = (const float*)d_in[8];
  float* out = (float*)d_out;

  char* p = (char*)d_ws;
  unsigned short* xbf   = (unsigned short*)p; p += (size_t)Bb * Ss * Ff * 2;  // 16 MB
  unsigned short* w1t   = (unsigned short*)p; p += (size_t)H1 * KD1 * 2;      // 2 MB
  unsigned short* w2t   = (unsigned short*)p; p += (size_t)H2 * H1 * 2;       // 0.25 MB
  float*          dbias = (float*)p;          p += (size_t)Ss * H1 * 4;       // 1 MB
  unsigned*       mrelu = (unsigned*)p;       p += (size_t)Bb * H2 * 4;       // 0.25 MB
  unsigned short* h1    = (unsigned short*)p; p += (size_t)Mtot * H1 * 2;     // 134 MB

  hipMemsetAsync(mrelu, 0, (size_t)Bb * H2 * 4, stream);
  k_cvt_x<<<(Bb * Ss * Ff / 4) / 256, 256, 0, stream>>>(x, xbf);
  k_w1t<<<(H1 * KD1) / 256, 256, 0, stream>>>(W1, w1t);
  k_w2t<<<(H2 * H1) / 256, 256, 0, stream>>>(W2, w2t);
  k_dbias<<<(Ss * H1) / 256, 256, 0, stream>>>(W1, b1, dist, dbias);
  k_gemm1<<<(Mtot / 128) * (H1 / 128), 256, 0, stream>>>(xbf, w1t, nb, dbias, h1);
  k_gemm2<<<(Mtot / 128) * (H2 / 128), 256, 0, stream>>>(h1, w2t, b2, mrelu);
  k_final<<<Bb, 256, 0, stream>>>(mrelu, Wd, bd, out);
}

// Round 4
// 442.764 us; speedup vs baseline: 1.0470x; 1.0470x over previous
//
#include <hip/hip_runtime.h>

typedef __attribute__((ext_vector_type(8))) short short8;
typedef __attribute__((ext_vector_type(4))) float f32x4;

constexpr int Bb = 256, Ss = 512, Kk = 32, Ff = 64, H1 = 512, H2 = 256;
constexpr int Mtot = Bb * Ss;   // 131072
constexpr int Mh = Mtot / 2;    // 65536 rows per half (h1 buffer reuse)
constexpr int KD1 = Kk * Ff;    // 2048

#define DEVI static __device__ __forceinline__

DEVI unsigned short f2b(float f) {
  unsigned u = __float_as_uint(f);
  return (unsigned short)((u + 0x7FFFu + ((u >> 16) & 1u)) >> 16);
}

DEVI void stage16(const void* g, void* l) {
  __builtin_amdgcn_global_load_lds((const __attribute__((address_space(1))) void*)g,
                                   (__attribute__((address_space(3))) void*)l, 16, 0, 0);
}

// ---------- precompute kernels ----------
__global__ void k_cvt_x(const float* __restrict__ x, unsigned short* __restrict__ xbf) {
  int i = blockIdx.x * 256 + threadIdx.x;  // over 2097152 float4 groups
  float4 v = ((const float4*)x)[i];
  ushort4 o;
  o.x = f2b(v.x); o.y = f2b(v.y); o.z = f2b(v.z); o.w = f2b(v.w);
  ((ushort4*)xbf)[i] = o;
}

// w1t[h][k*64+f] = W1[k*65+f][h]  (strip distance rows, transpose, bf16)
__global__ void k_w1t(const float* __restrict__ W1, unsigned short* __restrict__ w1t) {
  int idx = blockIdx.x * 256 + threadIdx.x;  // 512*2048
  int h = idx >> 11, i = idx & 2047;
  int k = i >> 6, f = i & 63;
  w1t[idx] = f2b(W1[(k * 65 + f) * 512 + h]);
}

// w2t[n][k] = W2[k][n]
__global__ void k_w2t(const float* __restrict__ W2, unsigned short* __restrict__ w2t) {
  int idx = blockIdx.x * 256 + threadIdx.x;  // 256*512
  int n = idx >> 9, k = idx & 511;
  w2t[idx] = f2b(W2[k * 256 + n]);
}

// dbias[s][h] = b1[h] + sum_k dist[s][k] * W1[k*65+64][h]   (fp32)
__global__ void k_dbias(const float* __restrict__ W1, const float* __restrict__ b1,
                        const float* __restrict__ dist, float* __restrict__ dbias) {
  int idx = blockIdx.x * 256 + threadIdx.x;  // 512*512
  int s = idx >> 9, h = idx & 511;
  float a = b1[h];
  #pragma unroll
  for (int k = 0; k < 32; ++k)
    a += dist[s * 32 + k] * W1[(k * 65 + 64) * 512 + h];
  dbias[idx] = a;
}

// LDS layout note (both GEMMs): tile rows are 128 B (64 bf16). Stored 16-B
// chunk position p of row r holds GLOBAL chunk (p ^ (r&7)).  global_load_lds
// dest is linear (wave base + lane*16), so the swizzle is applied on the
// per-lane GLOBAL source address; ds_read applies the same XOR (rule #21).

// ---------- GEMM1: h1 = relu(gather(xbf) @ w1t^T + dbias) over rows [mbase, mbase+Mh) ----------
__global__ __launch_bounds__(256, 2) void k_gemm1(
    const unsigned short* __restrict__ xbf, const unsigned short* __restrict__ w1t,
    const int* __restrict__ nb, const float* __restrict__ dbias,
    unsigned short* __restrict__ h1, int mbase) {
  __shared__ __align__(16) unsigned short As[128 * 64];
  __shared__ __align__(16) unsigned short Bs[128 * 64];
  const int tid = threadIdx.x;
  const int lane = tid & 63;
  const int w = tid >> 6;
  const int wm = w >> 1, wn = w & 1;
  const int mblk = blockIdx.x >> 2;
  const int nblk = blockIdx.x & 3;
  const int r0l = mblk << 7;           // local row base within this half
  const int r0g = mbase + r0l;         // global bs row; single batch b per tile (128 | 512)
  const int b = r0g >> 9;
  const int s0 = r0g & 511;
  const int ncol0 = nblk << 7;
  const int arow = lane >> 3;                              // row within 8-row staging group
  const int scol = (((lane & 7) ^ (lane >> 3)) << 3);      // swizzled source chunk (elements)

  f32x4 acc[4][4];
  #pragma unroll
  for (int m = 0; m < 4; ++m)
    #pragma unroll
    for (int n = 0; n < 4; ++n) acc[m][n] = (f32x4){0.f, 0.f, 0.f, 0.f};

  for (int t = 0; t < 32; ++t) {       // K-step = one neighbor's 64 features
    #pragma unroll
    for (int i = 0; i < 4; ++i) {      // A: gather rows xbf[b, nb[s,t], :]
      int rr = (w << 5) + (i << 3);
      int row = rr + arow;
      int j = nb[((s0 + row) << 5) + t];
      stage16(xbf + (((size_t)((b << 9) + j)) << 6) + scol, As + rr * 64);
    }
    #pragma unroll
    for (int i = 0; i < 4; ++i) {      // B^T tile: w1t rows ncol0..+127, k-cols t*64..+63
      int rr = (w << 5) + (i << 3);
      int row = rr + arow;
      stage16(w1t + (((size_t)(ncol0 + row)) << 11) + (t << 6) + scol, Bs + rr * 64);
    }
    asm volatile("s_waitcnt vmcnt(0)" ::: "memory");   // force stage completion pre-barrier
    __syncthreads();
    #pragma unroll
    for (int ks = 0; ks < 2; ++ks) {
      const int rdoff = ((((ks << 2) + (lane >> 4)) ^ (lane & 7)) << 3);  // swizzled read chunk
      short8 af[4], bfr[4];
      #pragma unroll
      for (int m = 0; m < 4; ++m)
        af[m] = *(const short8*)(As + ((wm << 6) + (m << 4) + (lane & 15)) * 64 + rdoff);
      #pragma unroll
      for (int n = 0; n < 4; ++n)
        bfr[n] = *(const short8*)(Bs + ((wn << 6) + (n << 4) + (lane & 15)) * 64 + rdoff);
      #pragma unroll
      for (int m = 0; m < 4; ++m)
        #pragma unroll
        for (int n = 0; n < 4; ++n)
          acc[m][n] = __builtin_amdgcn_mfma_f32_16x16x32_bf16(af[m], bfr[n], acc[m][n], 0, 0, 0);
    }
    __syncthreads();
  }

  #pragma unroll
  for (int m = 0; m < 4; ++m) {
    int rowl = (wm << 6) + (m << 4) + ((lane >> 4) << 2);
    #pragma unroll
    for (int n = 0; n < 4; ++n) {
      int col = ncol0 + (wn << 6) + (n << 4) + (lane & 15);
      #pragma unroll
      for (int r = 0; r < 4; ++r) {
        int rowL = r0l + rowl + r;                       // local row for h1 store
        float v = acc[m][n][r] + dbias[(((r0g + rowl + r) & 511) << 9) + col];
        v = v > 0.f ? v : 0.f;
        h1[((size_t)rowL << 9) + col] = f2b(v);
      }
    }
  }
}

// ---------- GEMM2 + fused max-over-S over rows [mbase, mbase+Mh) ----------
__global__ __launch_bounds__(256, 2) void k_gemm2(
    const unsigned short* __restrict__ h1, const unsigned short* __restrict__ w2t,
    const float* __restrict__ b2, unsigned* __restrict__ mrelu, int mbase) {
  __shared__ __align__(16) unsigned short As[128 * 64];
  __shared__ __align__(16) unsigned short Bs[128 * 64];
  const int tid = threadIdx.x;
  const int lane = tid & 63;
  const int w = tid >> 6;
  const int wm = w >> 1, wn = w & 1;
  const int mblk = blockIdx.x >> 1;
  const int nblk = blockIdx.x & 1;
  const int r0l = mblk << 7;
  const int b = (mbase + r0l) >> 9;
  const int ncol0 = nblk << 7;
  const int arow = lane >> 3;
  const int scol = (((lane & 7) ^ (lane >> 3)) << 3);

  f32x4 acc[4][4];
  #pragma unroll
  for (int m = 0; m < 4; ++m)
    #pragma unroll
    for (int n = 0; n < 4; ++n) acc[m][n] = (f32x4){0.f, 0.f, 0.f, 0.f};

  for (int t = 0; t < 8; ++t) {
    #pragma unroll
    for (int i = 0; i < 4; ++i) {
      int rr = (w << 5) + (i << 3);
      int row = rr + arow;
      stage16(h1 + (((size_t)(r0l + row)) << 9) + (t << 6) + scol, As + rr * 64);
      stage16(w2t + (((size_t)(ncol0 + row)) << 9) + (t << 6) + scol, Bs + rr * 64);
    }
    asm volatile("s_waitcnt vmcnt(0)" ::: "memory");
    __syncthreads();
    #pragma unroll
    for (int ks = 0; ks < 2; ++ks) {
      const int rdoff = ((((ks << 2) + (lane >> 4)) ^ (lane & 7)) << 3);
      short8 af[4], bfr[4];
      #pragma unroll
      for (int m = 0; m < 4; ++m)
        af[m] = *(const short8*)(As + ((wm << 6) + (m << 4) + (lane & 15)) * 64 + rdoff);
      #pragma unroll
      for (int n = 0; n < 4; ++n)
        bfr[n] = *(const short8*)(Bs + ((wn << 6) + (n << 4) + (lane & 15)) * 64 + rdoff);
      #pragma unroll
      for (int m = 0; m < 4; ++m)
        #pragma unroll
        for (int n = 0; n < 4; ++n)
          acc[m][n] = __builtin_amdgcn_mfma_f32_16x16x32_bf16(af[m], bfr[n], acc[m][n], 0, 0, 0);
    }
    __syncthreads();
  }

  // column max over this wave's 64 rows, then atomicMax into per-batch table
  #pragma unroll
  for (int n = 0; n < 4; ++n) {
    int col = ncol0 + (wn << 6) + (n << 4) + (lane & 15);
    float cm = -1e30f;
    #pragma unroll
    for (int m = 0; m < 4; ++m)
      #pragma unroll
      for (int r = 0; r < 4; ++r) cm = fmaxf(cm, acc[m][n][r]);
    cm = fmaxf(cm, __shfl_xor(cm, 16));
    cm = fmaxf(cm, __shfl_xor(cm, 32));
    if ((lane >> 4) == 0) {
      float v = fmaxf(cm + b2[col], 0.f);   // relu folded: table init 0, bits monotone for >=0
      atomicMax(mrelu + ((b << 8) + col), __float_as_uint(v));
    }
  }
}

// ---------- final: out[b] = relu(m[b,:]) . Wd + bd  (fp32) ----------
__global__ void k_final(const unsigned* __restrict__ mrelu, const float* __restrict__ wd,
                        const float* __restrict__ bd, float* __restrict__ out) {
  int b = blockIdx.x, t = threadIdx.x;
  float v = __uint_as_float(mrelu[(b << 8) + t]) * wd[t];
  #pragma unroll
  for (int o = 32; o > 0; o >>= 1) v += __shfl_down(v, o);
  __shared__ float p[4];
  if ((t & 63) == 0) p[t >> 6] = v;
  __syncthreads();
  if (t == 0) out[b] = p[0] + p[1] + p[2] + p[3] + bd[0];
}

extern "C" void kernel_launch(void* const* d_in, const int* in_sizes, int n_in,
                              void* d_out, int out_size, void* d_ws, size_t ws_size,
                              hipStream_t stream) {
  (void)in_sizes; (void)n_in; (void)out_size; (void)ws_size;
  const float* x    = (const float*)d_in[0];
  const int*   nb   = (const int*)d_in[1];
  const float* dist = (const float*)d_in[2];
  const float* W1   = (const float*)d_in[3];
  const float* b1   = (const float*)d_in[4];
  const float* W2   = (const float*)d_in[5];
  const float* b2   = (const float*)d_in[6];
  const float* Wd   = (const float*)d_in[7];
  const float* bd   = (const float*)d_in[8];
  float* out = (float*)d_out;

  // ws usage: 16 + 2 + 0.25 + 1 + 0.25 + 64 = ~83.6 MB
  char* p = (char*)d_ws;
  unsigned short* xbf   = (unsigned short*)p; p += (size_t)Bb * Ss * Ff * 2;  // 16 MB
  unsigned short* w1t   = (unsigned short*)p; p += (size_t)H1 * KD1 * 2;      // 2 MB
  unsigned short* w2t   = (unsigned short*)p; p += (size_t)H2 * H1 * 2;       // 0.25 MB
  float*          dbias = (float*)p;          p += (size_t)Ss * H1 * 4;       // 1 MB
  unsigned*       mrelu = (unsigned*)p;       p += (size_t)Bb * H2 * 4;       // 0.25 MB
  unsigned short* h1    = (unsigned short*)p; p += (size_t)Mh * H1 * 2;       // 64 MB (reused per half)

  hipMemsetAsync(mrelu, 0, (size_t)Bb * H2 * 4, stream);
  k_cvt_x<<<(Bb * Ss * Ff / 4) / 256, 256, 0, stream>>>(x, xbf);
  k_w1t<<<(H1 * KD1) / 256, 256, 0, stream>>>(W1, w1t);
  k_w2t<<<(H2 * H1) / 256, 256, 0, stream>>>(W2, w2t);
  k_dbias<<<(Ss * H1) / 256, 256, 0, stream>>>(W1, b1, dist, dbias);
  for (int hh = 0; hh < 2; ++hh) {
    int mbase = hh * Mh;
    k_gemm1<<<(Mh / 128) * (H1 / 128), 256, 0, stream>>>(xbf, w1t, nb, dbias, h1, mbase);
    k_gemm2<<<(Mh / 128) * (H2 / 128), 256, 0, stream>>>(h1, w2t, b2, mrelu, mbase);
  }
  k_final<<<Bb, 256, 0, stream>>>(mrelu, Wd, bd, out);
}

// Round 6
// 408.679 us; speedup vs baseline: 1.1344x; 1.0834x over previous
//
#include <hip/hip_runtime.h>

typedef __attribute__((ext_vector_type(8))) short short8;
typedef __attribute__((ext_vector_type(4))) float f32x4;

constexpr int Bb = 256, Ss = 512, Kk = 32, Ff = 64, H1 = 512, H2 = 256;
constexpr int Mtot = Bb * Ss;   // 131072
constexpr int Mh = Mtot / 2;    // 65536 rows per half (h1 buffer reuse)
constexpr int KD1 = Kk * Ff;    // 2048

#define DEVI static __device__ __forceinline__
#define BARRIER asm volatile("s_barrier" ::: "memory")
#define VMCNT(N) asm volatile("s_waitcnt vmcnt(" #N ")" ::: "memory")

DEVI unsigned short f2b(float f) {
  unsigned u = __float_as_uint(f);
  return (unsigned short)((u + 0x7FFFu + ((u >> 16) & 1u)) >> 16);
}

DEVI void stage16(const void* g, void* l) {
  __builtin_amdgcn_global_load_lds((const __attribute__((address_space(1))) void*)g,
                                   (__attribute__((address_space(3))) void*)l, 16, 0, 0);
}

// ---------- precompute kernels ----------
__global__ void k_cvt_x(const float* __restrict__ x, unsigned short* __restrict__ xbf) {
  int i = blockIdx.x * 256 + threadIdx.x;
  float4 v = ((const float4*)x)[i];
  ushort4 o;
  o.x = f2b(v.x); o.y = f2b(v.y); o.z = f2b(v.z); o.w = f2b(v.w);
  ((ushort4*)xbf)[i] = o;
}

__global__ void k_w1t(const float* __restrict__ W1, unsigned short* __restrict__ w1t) {
  int idx = blockIdx.x * 256 + threadIdx.x;  // 512*2048
  int h = idx >> 11, i = idx & 2047;
  int k = i >> 6, f = i & 63;
  w1t[idx] = f2b(W1[(k * 65 + f) * 512 + h]);
}

__global__ void k_w2t(const float* __restrict__ W2, unsigned short* __restrict__ w2t) {
  int idx = blockIdx.x * 256 + threadIdx.x;  // 256*512
  int n = idx >> 9, k = idx & 511;
  w2t[idx] = f2b(W2[k * 256 + n]);
}

__global__ void k_dbias(const float* __restrict__ W1, const float* __restrict__ b1,
                        const float* __restrict__ dist, float* __restrict__ dbias) {
  int idx = blockIdx.x * 256 + threadIdx.x;  // 512*512
  int s = idx >> 9, h = idx & 511;
  float a = b1[h];
  #pragma unroll
  for (int k = 0; k < 32; ++k)
    a += dist[s * 32 + k] * W1[(k * 65 + 64) * 512 + h];
  dbias[idx] = a;
}

// LDS swizzle (both GEMMs, proven 0-conflict in R4): rows are 64 bf16 (8
// 16-B chunks). Stored chunk p of row r holds GLOBAL chunk p ^ (r&7);
// global_load_lds dest stays linear, swizzle applied on per-lane global
// source; ds_read applies the same XOR (rule #21).

// ---------- GEMM1, 256^2 8-phase: h1 = relu(gather(xbf) @ w1t^T + dbias) ----------
// rows [mbase, mbase+Mh). 512 thr / 8 waves (2M x 4N), BK=64, 2x64KB LDS dbuf.
// Per K-tile 4 phases (ks,mq). Staging unit = 64 rows (1 gload_lds/wave).
// Issue order (tile t+1 during tile t): ph0:A0,A2  ph1:B0,B1  ph2:B2,B3  ph3:A1,A3.
// Per-wave vmcnt ledger (nb prefetch loads included, they precede the stages):
//   vmcnt(2) at ph0 end -> A1,A3(t) landed for ph1 reads;
//   vmcnt(2) at ph3 end -> A0,A2,B0..B3(t+1) landed for next ph0 reads.
// Buffer t+1 writes start only after tile t's final barrier on buffer cur: safe.
__global__ __launch_bounds__(512, 2) void k_gemm1(
    const unsigned short* __restrict__ xbf, const unsigned short* __restrict__ w1t,
    const int* __restrict__ nb, const float* __restrict__ dbias,
    unsigned short* __restrict__ h1, int mbase) {
  __shared__ __align__(16) unsigned short lds[2][2][256 * 64];  // 128 KiB
  const int tid = threadIdx.x;
  const int lane = tid & 63;
  const int w = tid >> 6;            // 0..7
  const int wm = w >> 2, wn = w & 3;
  const int mblk = blockIdx.x >> 1;
  const int nblk = blockIdx.x & 1;
  const int r0l = mblk << 8;         // local row base (256 rows/tile)
  const int r0g = mbase + r0l;
  const int b = r0g >> 9;
  const int s0 = r0g & 511;          // 0 or 256; s0+255 <= 511
  const int ncol0 = nblk << 8;
  const int scol8 = (((lane & 7) ^ ((lane >> 3) & 7)) << 3);

  int nbi[4];
  #pragma unroll
  for (int u = 0; u < 4; ++u)
    nbi[u] = (s0 + (u << 6) + (w << 3) + (lane >> 3)) << 5;  // *32

  f32x4 acc[8][4];
  #pragma unroll
  for (int m = 0; m < 8; ++m)
    #pragma unroll
    for (int n = 0; n < 4; ++n) acc[m][n] = (f32x4){0.f, 0.f, 0.f, 0.f};

  // ---- prologue: stage tile 0 into lds[0]; preload j4 for tile 1
  #pragma unroll
  for (int u = 0; u < 4; ++u) {
    int j = nb[nbi[u]];
    stage16(xbf + (((size_t)((b << 9) + j)) << 6) + scol8,
            &lds[0][0][(u << 12) + (w << 9)]);
  }
  #pragma unroll
  for (int u = 0; u < 4; ++u)
    stage16(w1t + (((size_t)(ncol0 + (u << 6) + (w << 3) + (lane >> 3))) << 11) + scol8,
            &lds[0][1][(u << 12) + (w << 9)]);
  int j4[4];
  #pragma unroll
  for (int u = 0; u < 4; ++u) j4[u] = nb[nbi[u] + 1];
  VMCNT(0);
  BARRIER;

  for (int t = 0; t < 32; ++t) {
    unsigned short* As = &lds[t & 1][0][0];
    unsigned short* Bs = &lds[t & 1][1][0];
    unsigned short* An = &lds[(t & 1) ^ 1][0][0];
    unsigned short* Bn = &lds[(t & 1) ^ 1][1][0];
    const bool pf = (t < 31);
    short8 a[4], bq[4];
    int jn[4];

#define RD_A(mq, ks)                                                             \
    _Pragma("unroll")                                                            \
    for (int i = 0; i < 4; ++i)                                                  \
      a[i] = *(const short8*)(As + ((wm << 7) + ((mq) << 6) + (i << 4) +         \
               (lane & 15)) * 64 + (((((ks) << 2) + (lane >> 4)) ^ (lane & 7)) << 3));
#define RD_B(ks)                                                                 \
    _Pragma("unroll")                                                            \
    for (int n = 0; n < 4; ++n)                                                  \
      bq[n] = *(const short8*)(Bs + ((wn << 6) + (n << 4) + (lane & 15)) * 64 +  \
               (((((ks) << 2) + (lane >> 4)) ^ (lane & 7)) << 3));
#define STA(u) stage16(xbf + (((size_t)((b << 9) + j4[u])) << 6) + scol8,        \
                       An + ((u) << 12) + (w << 9))
#define STB(u) stage16(w1t + (((size_t)(ncol0 + ((u) << 6) + (w << 3) +          \
                       (lane >> 3))) << 11) + ((t + 1) << 6) + scol8,            \
                       Bn + ((u) << 12) + (w << 9))
#define MM(mq)                                                                   \
    _Pragma("unroll")                                                            \
    for (int i = 0; i < 4; ++i)                                                  \
      _Pragma("unroll")                                                          \
      for (int n = 0; n < 4; ++n)                                                \
        acc[((mq) << 2) + i][n] = __builtin_amdgcn_mfma_f32_16x16x32_bf16(       \
            a[i], bq[n], acc[((mq) << 2) + i][n], 0, 0, 0);

    // ---- ph0: ks=0 mq=0
    RD_A(0, 0); RD_B(0);
    if (pf) { STA(0); STA(2); VMCNT(2); } else { VMCNT(0); }
    BARRIER;
    __builtin_amdgcn_s_setprio(1); MM(0); __builtin_amdgcn_s_setprio(0);
    BARRIER;
    // ---- ph1: ks=0 mq=1
    RD_A(1, 0);
    if (pf) { STB(0); STB(1); }
    BARRIER;
    __builtin_amdgcn_s_setprio(1); MM(1); __builtin_amdgcn_s_setprio(0);
    BARRIER;
    // ---- ph2: ks=1 mq=0
    RD_A(0, 1); RD_B(1);
    {
      int tt = (t + 2 < 32) ? (t + 2) : 31;
      #pragma unroll
      for (int u = 0; u < 4; ++u) jn[u] = nb[nbi[u] + tt];
    }
    if (pf) { STB(2); STB(3); }
    BARRIER;
    __builtin_amdgcn_s_setprio(1); MM(0); __builtin_amdgcn_s_setprio(0);
    BARRIER;
    // ---- ph3: ks=1 mq=1
    RD_A(1, 1);
    if (pf) { STA(1); STA(3); VMCNT(2); }
    BARRIER;
    __builtin_amdgcn_s_setprio(1); MM(1); __builtin_amdgcn_s_setprio(0);
    BARRIER;

    #pragma unroll
    for (int u = 0; u < 4; ++u) j4[u] = jn[u];
#undef RD_A
#undef RD_B
#undef STA
#undef STB
#undef MM
  }

  // ---- epilogue
  #pragma unroll
  for (int fm = 0; fm < 8; ++fm) {
    int rowl = (wm << 7) + (fm << 4) + ((lane >> 4) << 2);
    #pragma unroll
    for (int n = 0; n < 4; ++n) {
      int col = ncol0 + (wn << 6) + (n << 4) + (lane & 15);
      #pragma unroll
      for (int r = 0; r < 4; ++r) {
        int rl = rowl + r;
        float v = acc[fm][n][r] + dbias[((((r0g + rl) & 511)) << 9) + col];
        v = v > 0.f ? v : 0.f;
        h1[((size_t)(r0l + rl) << 9) + col] = f2b(v);
      }
    }
  }
}

// ---------- GEMM2 (BN=256 single-pass) + fused max-over-S ----------
__global__ __launch_bounds__(256, 2) void k_gemm2(
    const unsigned short* __restrict__ h1, const unsigned short* __restrict__ w2t,
    const float* __restrict__ b2, unsigned* __restrict__ mrelu, int mbase) {
  __shared__ __align__(16) unsigned short As[128 * 64];   // 16 KB
  __shared__ __align__(16) unsigned short Bs[256 * 64];   // 32 KB
  const int tid = threadIdx.x;
  const int lane = tid & 63;
  const int w = tid >> 6;            // 0..3, wave covers cols w*64..+63
  const int r0l = blockIdx.x << 7;
  const int b = (mbase + r0l) >> 9;
  const int scol8 = (((lane & 7) ^ ((lane >> 3) & 7)) << 3);

  f32x4 acc[8][4];
  #pragma unroll
  for (int m = 0; m < 8; ++m)
    #pragma unroll
    for (int n = 0; n < 4; ++n) acc[m][n] = (f32x4){0.f, 0.f, 0.f, 0.f};

  for (int t = 0; t < 8; ++t) {
    #pragma unroll
    for (int a2 = 0; a2 < 4; ++a2)   // A rows 0..127 (w*32 + a2*8 + lane>>3)
      stage16(h1 + (((size_t)(r0l + (w << 5) + (a2 << 3) + (lane >> 3))) << 9) +
                  (t << 6) + scol8,
              As + (w << 11) + (a2 << 9));
    #pragma unroll
    for (int b2i = 0; b2i < 8; ++b2i)  // B rows 0..255 (w*64 + b2i*8 + lane>>3)
      stage16(w2t + (((size_t)((w << 6) + (b2i << 3) + (lane >> 3))) << 9) +
                  (t << 6) + scol8,
              Bs + (w << 12) + (b2i << 9));
    VMCNT(0);
    __syncthreads();
    #pragma unroll
    for (int ks = 0; ks < 2; ++ks) {
      const int rdoff = ((((ks << 2) + (lane >> 4)) ^ (lane & 7)) << 3);
      short8 af[8], bf[4];
      #pragma unroll
      for (int fm = 0; fm < 8; ++fm)
        af[fm] = *(const short8*)(As + ((fm << 4) + (lane & 15)) * 64 + rdoff);
      #pragma unroll
      for (int n = 0; n < 4; ++n)
        bf[n] = *(const short8*)(Bs + ((w << 6) + (n << 4) + (lane & 15)) * 64 + rdoff);
      #pragma unroll
      for (int fm = 0; fm < 8; ++fm)
        #pragma unroll
        for (int n = 0; n < 4; ++n)
          acc[fm][n] = __builtin_amdgcn_mfma_f32_16x16x32_bf16(af[fm], bf[n], acc[fm][n], 0, 0, 0);
    }
    __syncthreads();
  }

  #pragma unroll
  for (int n = 0; n < 4; ++n) {
    int col = (w << 6) + (n << 4) + (lane & 15);
    float cm = -1e30f;
    #pragma unroll
    for (int fm = 0; fm < 8; ++fm)
      #pragma unroll
      for (int r = 0; r < 4; ++r) cm = fmaxf(cm, acc[fm][n][r]);
    cm = fmaxf(cm, __shfl_xor(cm, 16));
    cm = fmaxf(cm, __shfl_xor(cm, 32));
    if ((lane >> 4) == 0) {
      float v = fmaxf(cm + b2[col], 0.f);
      atomicMax(mrelu + ((b << 8) + col), __float_as_uint(v));
    }
  }
}

// ---------- final: out[b] = relu(m[b,:]) . Wd + bd ----------
__global__ void k_final(const unsigned* __restrict__ mrelu, const float* __restrict__ wd,
                        const float* __restrict__ bd, float* __restrict__ out) {
  int b = blockIdx.x, t = threadIdx.x;
  float v = __uint_as_float(mrelu[(b << 8) + t]) * wd[t];
  #pragma unroll
  for (int o = 32; o > 0; o >>= 1) v += __shfl_down(v, o);
  __shared__ float p[4];
  if ((t & 63) == 0) p[t >> 6] = v;
  __syncthreads();
  if (t == 0) out[b] = p[0] + p[1] + p[2] + p[3] + bd[0];
}

extern "C" void kernel_launch(void* const* d_in, const int* in_sizes, int n_in,
                              void* d_out, int out_size, void* d_ws, size_t ws_size,
                              hipStream_t stream) {
  (void)in_sizes; (void)n_in; (void)out_size; (void)ws_size;
  const float* x    = (const float*)d_in[0];
  const int*   nb   = (const int*)d_in[1];
  const float* dist = (const float*)d_in[2];
  const float* W1   = (const float*)d_in[3];
  const float* b1   = (const float*)d_in[4];
  const float* W2   = (const float*)d_in[5];
  const float* b2   = (const float*)d_in[6];
  const float* Wd   = (const float*)d_in[7];
  const float* bd   = (const float*)d_in[8];
  float* out = (float*)d_out;

  // ws usage: 16 + 2 + 0.25 + 1 + 0.25 + 64 = ~83.6 MB
  char* p = (char*)d_ws;
  unsigned short* xbf   = (unsigned short*)p; p += (size_t)Bb * Ss * Ff * 2;
  unsigned short* w1t   = (unsigned short*)p; p += (size_t)H1 * KD1 * 2;
  unsigned short* w2t   = (unsigned short*)p; p += (size_t)H2 * H1 * 2;
  float*          dbias = (float*)p;          p += (size_t)Ss * H1 * 4;
  unsigned*       mrelu = (unsigned*)p;       p += (size_t)Bb * H2 * 4;
  unsigned short* h1    = (unsigned short*)p; p += (size_t)Mh * H1 * 2;

  hipMemsetAsync(mrelu, 0, (size_t)Bb * H2 * 4, stream);
  k_cvt_x<<<(Bb * Ss * Ff / 4) / 256, 256, 0, stream>>>(x, xbf);
  k_w1t<<<(H1 * KD1) / 256, 256, 0, stream>>>(W1, w1t);
  k_w2t<<<(H2 * H1) / 256, 256, 0, stream>>>(W2, w2t);
  k_dbias<<<(Ss * H1) / 256, 256, 0, stream>>>(W1, b1, dist, dbias);
  for (int hh = 0; hh < 2; ++hh) {
    int mbase = hh * Mh;
    k_gemm1<<<(Mh / 256) * (H1 / 256), 512, 0, stream>>>(xbf, w1t, nb, dbias, h1, mbase);
    k_gemm2<<<(Mh / 128), 256, 0, stream>>>(h1, w2t, b2, mrelu, mbase);
  }
  k_final<<<Bb, 256, 0, stream>>>(mrelu, Wd, bd, out);
}